// Round 1
// baseline (362.010 us; speedup 1.0000x reference)
//
#include <hip/hip_runtime.h>
#include <hip/hip_bf16.h>
#include <stdint.h>
#include <stddef.h>

typedef __hip_bfloat16 bf16;
typedef __attribute__((ext_vector_type(8))) short bf16x8;
typedef __attribute__((ext_vector_type(4))) float f32x4;

namespace {
constexpr int kB = 32, kC = 256, kH = 56, kW = 56, kOC = 256, kR = 64;
constexpr int kHP = 58, kWP = 58;
constexpr int kPlane = kH * kW;            // 3136
constexpr int kNPix  = kB * kPlane;        // 100352
constexpr int kBM = 128, kBN = 128, kBK = 32;
constexpr int kKSteps = 9 * (kC / kBK);    // 72
}

// global -> LDS direct load, 16B per lane. lds ptr must be wave-uniform;
// HW writes at lds_base + lane*16. Global src is per-lane.
__device__ __forceinline__ void gload16(const void* g, void* lds_wave_uniform) {
    __builtin_amdgcn_global_load_lds(
        (const __attribute__((address_space(1))) uint32_t*)(uintptr_t)g,
        (__attribute__((address_space(3))) uint32_t*)(uint32_t)(uintptr_t)lds_wave_uniform,
        16, 0, 0);
}

// ---- Kernel A: merge U,V -> Wb[tap][oc][c] (bf16) ----
__global__ void merge_weights(const float* __restrict__ U, const float* __restrict__ V,
                              bf16* __restrict__ Wb) {
    const int tap = blockIdx.x >> 8;   // 0..8
    const int o   = blockIdx.x & 255;
    const int c   = threadIdx.x;       // 0..255
    const float* u = U + (size_t)(tap * kOC + o) * kR;       // U[tap][o][r]
    const float* v = V + (size_t)(tap * kR) * kC + c;        // V[tap][r][c]
    float acc = 0.f;
#pragma unroll
    for (int r = 0; r < kR; ++r) acc += u[r] * v[r * kC];
    Wb[(size_t)(tap * kOC + o) * kC + c] = __float2bfloat16(acc);
}

// ---- Kernel B: NCHW f32 -> padded NHWC bf16 xt[b][58][58][256] ----
__global__ void pad_nhwc(const float* __restrict__ x, bf16* __restrict__ xt) {
    const int b  = blockIdx.x / kHP;
    const int hp = blockIdx.x % kHP;
    const int c  = threadIdx.x;        // 0..255
    bf16* dst = xt + ((size_t)(b * kHP + hp)) * (kWP * kC) + c;
    const bf16 zero = __float2bfloat16(0.f);
    if (hp == 0 || hp == kHP - 1) {
        for (int wp = 0; wp < kWP; ++wp) dst[(size_t)wp * kC] = zero;
        return;
    }
    const int h = hp - 1;
    dst[0] = zero;
    dst[(size_t)(kWP - 1) * kC] = zero;
    const float* src = x + ((size_t)(b * kC + c) * kH + h) * kW;
    for (int w0 = 0; w0 < kW; w0 += 4) {
        const float4 v4 = *reinterpret_cast<const float4*>(src + w0);
        dst[(size_t)(w0 + 1) * kC] = __float2bfloat16(v4.x);
        dst[(size_t)(w0 + 2) * kC] = __float2bfloat16(v4.y);
        dst[(size_t)(w0 + 3) * kC] = __float2bfloat16(v4.z);
        dst[(size_t)(w0 + 4) * kC] = __float2bfloat16(v4.w);
    }
}

// ---- Kernel C: implicit GEMM  out[oc][pixel] = sum_k Wb[oc][k] * xt_gather[k][pixel] ----
// M = OC(256) tiled 128, N = pixels(100352) tiled 128, K = 9 taps * 256 c (tap-major).
__global__ __launch_bounds__(256, 2)
void conv_mfma(const bf16* __restrict__ Wb, const bf16* __restrict__ xt,
               float* __restrict__ out) {
    __shared__ bf16 Asm[kBM * kBK];   // [oc][c]    rows of 32 bf16 (64B)
    __shared__ bf16 Bsm[kBN * kBK];   // [pixel][c]

    const int tid  = threadIdx.x;
    const int lane = tid & 63;
    const int wid  = tid >> 6;
    const int p0   = blockIdx.x * kBN;
    const int ocb  = blockIdx.y * kBM;

    // staging: wave w fills LDS chunks 2w,2w+1 (1KB each), lane -> 16B slot
    const int row1 = wid * 32 + (lane >> 2);   // tile row for chunk 2w
    const int row2 = row1 + 16;                // tile row for chunk 2w+1
    const int coff = (lane & 3) * 8;           // c offset within 32

    const bf16* gA1 = Wb + (size_t)(ocb + row1) * kC + coff;
    const bf16* gA2 = Wb + (size_t)(ocb + row2) * kC + coff;

    const int gp1 = p0 + row1;
    const int gp2 = p0 + row2;
    const int b1 = gp1 / kPlane, q1 = gp1 - b1 * kPlane;
    const int b2 = gp2 / kPlane, q2 = gp2 - b2 * kPlane;
    const int h1 = q1 / kW, w1 = q1 - h1 * kW;
    const int h2 = q2 / kW, w2 = q2 - h2 * kW;
    const bf16* gB1 = xt + ((size_t)((b1 * kHP + h1) * kWP + w1)) * kC + coff;
    const bf16* gB2 = xt + ((size_t)((b2 * kHP + h2) * kWP + w2)) * kC + coff;

    char* AsmB = (char*)Asm + wid * 2048;
    char* BsmB = (char*)Bsm + wid * 2048;

    const int wr = wid >> 1, wc = wid & 1;     // wave -> 64x64 subtile
    const int lrow = lane & 15;
    const int lk   = (lane >> 4) * 8;

    f32x4 acc[4][4] = {};

    for (int ks = 0; ks < kKSteps; ++ks) {
        const int tap  = ks >> 3;
        const int c0   = (ks & 7) * kBK;
        const int aoff = tap * (kOC * kC) + c0;                      // elements
        const int boff = ((tap / 3) * kWP + (tap % 3)) * kC + c0;    // shift (i,j)

        gload16(gA1 + aoff, AsmB);
        gload16(gA2 + aoff, AsmB + 1024);
        gload16(gB1 + boff, BsmB);
        gload16(gB2 + boff, BsmB + 1024);
        __syncthreads();   // drains vmcnt -> LDS tiles ready

        bf16x8 af[4], bfr[4];
#pragma unroll
        for (int mi = 0; mi < 4; ++mi)
            af[mi] = *(const bf16x8*)&Asm[(wr * 64 + mi * 16 + lrow) * kBK + lk];
#pragma unroll
        for (int nj = 0; nj < 4; ++nj)
            bfr[nj] = *(const bf16x8*)&Bsm[(wc * 64 + nj * 16 + lrow) * kBK + lk];
#pragma unroll
        for (int mi = 0; mi < 4; ++mi)
#pragma unroll
            for (int nj = 0; nj < 4; ++nj)
                acc[mi][nj] = __builtin_amdgcn_mfma_f32_16x16x32_bf16(
                    af[mi], bfr[nj], acc[mi][nj], 0, 0, 0);
        __syncthreads();   // protect LDS before next stage
    }

    // epilogue: C/D layout col=lane&15 (pixel), row=(lane>>4)*4+reg (oc)
#pragma unroll
    for (int nj = 0; nj < 4; ++nj) {
        const int gp = p0 + wc * 64 + nj * 16 + lrow;
        const int bb = gp / kPlane;
        const int qq = gp - bb * kPlane;
        float* ob = out + (size_t)bb * (kOC * kPlane) + qq;
#pragma unroll
        for (int mi = 0; mi < 4; ++mi) {
            const int o = ocb + wr * 64 + mi * 16 + (lane >> 4) * 4;
            float* op = ob + (size_t)o * kPlane;
#pragma unroll
            for (int r = 0; r < 4; ++r)
                op[(size_t)r * kPlane] = acc[mi][nj][r];
        }
    }
}

extern "C" void kernel_launch(void* const* d_in, const int* in_sizes, int n_in,
                              void* d_out, int out_size, void* d_ws, size_t ws_size,
                              hipStream_t stream) {
    const float* x = (const float*)d_in[0];
    const float* U = (const float*)d_in[1];
    const float* V = (const float*)d_in[2];
    float* out = (float*)d_out;

    // workspace layout
    bf16* Wb = (bf16*)d_ws;                                    // 9*256*256 bf16 = 1.18 MB
    bf16* xt = (bf16*)((char*)d_ws + (size_t)9 * kOC * kC * 2); // 32*58*58*256 bf16 = 55 MB

    merge_weights<<<dim3(9 * kOC), dim3(kC), 0, stream>>>(U, V, Wb);
    pad_nhwc<<<dim3(kB * kHP), dim3(kC), 0, stream>>>(x, xt);
    conv_mfma<<<dim3(kNPix / kBN, kOC / kBM), dim3(256), 0, stream>>>(Wb, xt, out);
}

// Round 2
// 344.056 us; speedup vs baseline: 1.0522x; 1.0522x over previous
//
#include <hip/hip_runtime.h>
#include <hip/hip_bf16.h>
#include <stdint.h>
#include <stddef.h>

typedef __hip_bfloat16 bf16;
typedef __attribute__((ext_vector_type(8))) short bf16x8;
typedef __attribute__((ext_vector_type(4))) float f32x4;

namespace {
constexpr int kB = 32, kC = 256, kH = 56, kW = 56, kOC = 256, kR = 64;
constexpr int kHP = 58, kWP = 58;
constexpr int kPlane = kH * kW;            // 3136
constexpr int kNPix  = kB * kPlane;        // 100352
constexpr int kBM = 128, kBN = 128, kBK = 32;
constexpr int kKSteps = 9 * (kC / kBK);    // 72
}

// global -> LDS direct load, 16B per lane. lds ptr must be wave-uniform;
// HW writes at lds_base + lane*16. Global src is per-lane.
__device__ __forceinline__ void gload16(const void* g, void* lds_wave_uniform) {
    __builtin_amdgcn_global_load_lds(
        (const __attribute__((address_space(1))) uint32_t*)(uintptr_t)g,
        (__attribute__((address_space(3))) uint32_t*)(uint32_t)(uintptr_t)lds_wave_uniform,
        16, 0, 0);
}

__device__ __forceinline__ unsigned short f2bf(float f) {
    union { float f; unsigned int u; } cv; cv.f = f;
    const unsigned int u = cv.u;
    return (unsigned short)((u + 0x7FFFu + ((u >> 16) & 1u)) >> 16);  // RNE
}

// ---- Kernel A: merge U,V -> Wb[tap][oc][c] (bf16) ----
__global__ void merge_weights(const float* __restrict__ U, const float* __restrict__ V,
                              bf16* __restrict__ Wb) {
    const int tap = blockIdx.x >> 8;   // 0..8
    const int o   = blockIdx.x & 255;
    const int c   = threadIdx.x;       // 0..255
    const float* u = U + (size_t)(tap * kOC + o) * kR;       // U[tap][o][r]
    const float* v = V + (size_t)(tap * kR) * kC + c;        // V[tap][r][c]
    float acc = 0.f;
#pragma unroll
    for (int r = 0; r < kR; ++r) acc += u[r] * v[r * kC];
    Wb[(size_t)(tap * kOC + o) * kC + c] = __float2bfloat16(acc);
}

// ---- Kernel B: NCHW f32 -> padded NHWC bf16 xt[b][58][58][256] ----
// LDS-transpose version: coalesced float4 reads, coalesced uint (2xbf16) writes.
__global__ __launch_bounds__(256)
void pad_nhwc(const float* __restrict__ x, bf16* __restrict__ xt) {
    const int b  = blockIdx.x / kHP;
    const int hp = blockIdx.x % kHP;
    const int tid = threadIdx.x;
    bf16* dst = xt + (size_t)(b * kHP + hp) * (kWP * kC);   // 29696 B, 16B aligned

    if (hp == 0 || hp == kHP - 1) {
        uint4* d4 = (uint4*)dst;
        constexpr int n16 = (kWP * kC * 2) / 16;  // 1856
        for (int i = tid; i < n16; i += 256) d4[i] = uint4{0, 0, 0, 0};
        return;
    }

    const int h = hp - 1;
    __shared__ unsigned short t[256][58];   // row stride 116B -> bank step 29 (coprime 32)

    const int w4 = tid & 15;        // float4 index within a row (14 active)
    const int cb = tid >> 4;        // 16 c's per pass
#pragma unroll
    for (int pass = 0; pass < 16; ++pass) {
        const int c = pass * 16 + cb;
        if (w4 < 14) {
            const float4 v = *reinterpret_cast<const float4*>(
                x + ((size_t)(b * kC + c) * kH + h) * kW + w4 * 4);
            t[c][w4 * 4 + 0] = f2bf(v.x);
            t[c][w4 * 4 + 1] = f2bf(v.y);
            t[c][w4 * 4 + 2] = f2bf(v.z);
            t[c][w4 * 4 + 3] = f2bf(v.w);
        }
    }
    __syncthreads();

    const int c2   = (tid & 127) * 2;   // pair of channels
    const int half = tid >> 7;          // which wp of the pair
    unsigned int* dw = (unsigned int*)dst;
#pragma unroll
    for (int wpi = 0; wpi < 29; ++wpi) {
        const int wp = wpi * 2 + half;  // 0..57
        unsigned int val = 0;
        if (wp >= 1 && wp <= kW) {
            const int w = wp - 1;
            val = (unsigned int)t[c2][w] | ((unsigned int)t[c2 + 1][w] << 16);
        }
        dw[(size_t)wp * 128 + (c2 >> 1)] = val;
    }
}

// ---- Kernel C: implicit GEMM  out[oc][pixel] = sum_k Wb[oc][k] * xt_gather[k][pixel]
// M = OC(256) tiled 128, N = pixels(100352) tiled 128, K = 9 taps * 256 c (tap-major).
// 2-phase double-buffered (T3-minimum), LDS XOR swizzle (T2), XCD swizzle (T1).
__global__ __launch_bounds__(256, 4)
void conv_mfma(const bf16* __restrict__ Wb, const bf16* __restrict__ xt,
               float* __restrict__ out) {
    __shared__ bf16 Asm[2][kBM * kBK];   // 2 x 8KB
    __shared__ bf16 Bsm[2][kBM * kBK];   // 2 x 8KB

    const int tid  = threadIdx.x;
    const int lane = tid & 63;
    const int wid  = tid >> 6;

    // grid: 1568 blocks. XCD-bijective swizzle (1568 % 8 == 0), then
    // oc-tile is the FAST dim so both M tiles of a pixel tile share an XCD/L2.
    const int bid = blockIdx.x;
    constexpr int cpx = (kNPix / kBN) * (kOC / kBM) / 8;   // 196
    const int swz = (bid & 7) * cpx + (bid >> 3);
    const int ocb = (swz & 1) * kBM;
    const int p0  = (swz >> 1) * kBN;

    // ---- staging geometry: wave w fills LDS chunks 2w,2w+1 (1KB each) ----
    // LDS dest is linear (lane*16). Source column is pre-swizzled with the
    // involution s(r,c) = c ^ ((r>>1)&3) so swizzled reads see global data.
    const int rowL = lane >> 2;                         // 0..15 within chunk
    const int row1 = wid * 32 + rowL;                   // tile row, chunk 2w
    const int sw   = (lane >> 3) & 3;                   // == ((row1>>1)&3)
    const int coff = (((lane & 3) ^ sw)) * 8;           // swizzled k-chunk (elems)

    const bf16* gA1 = Wb + (size_t)(ocb + row1) * kC + coff;   // +16*kC for chunk 2

    const int gp1 = p0 + row1;
    const int gp2 = gp1 + 16;
    const int b1 = gp1 / kPlane, q1 = gp1 - b1 * kPlane;
    const int b2 = gp2 / kPlane, q2 = gp2 - b2 * kPlane;
    const int h1 = q1 / kW, w1 = q1 - h1 * kW;
    const int h2 = q2 / kW, w2 = q2 - h2 * kW;
    const bf16* gB1 = xt + ((size_t)((b1 * kHP + h1) * kWP + w1)) * kC + coff;
    const bf16* gB2 = xt + ((size_t)((b2 * kHP + h2) * kWP + w2)) * kC + coff;

    // ---- fragment-read geometry (swizzled) ----
    const int wr = wid >> 1, wc = wid & 1;     // wave -> 64x64 subtile
    const int lrow = lane & 15;
    const int rcs  = (((lane >> 4) ^ ((lrow >> 1) & 3))) * 8;  // swizzled k offset

    f32x4 acc[4][4] = {};

    auto stage = [&](int buf, int ks) {
        const int tap  = ks >> 3;
        const int c0   = (ks & 7) * kBK;
        const int aoff = tap * (kOC * kC) + c0;                     // elements
        const int boff = ((tap / 3) * kWP + (tap % 3)) * kC + c0;   // shift (i,j)
        char* AsmB = (char*)(&Asm[buf][0]) + wid * 2048;
        char* BsmB = (char*)(&Bsm[buf][0]) + wid * 2048;
        gload16(gA1 + aoff,           AsmB);
        gload16(gA1 + aoff + 16 * kC, AsmB + 1024);
        gload16(gB1 + boff,           BsmB);
        gload16(gB2 + boff,           BsmB + 1024);
    };

    stage(0, 0);
    asm volatile("s_waitcnt vmcnt(0)\ns_barrier" ::: "memory");

    int cur = 0;
    for (int ks = 0; ks < kKSteps; ++ks) {
        if (ks + 1 < kKSteps) stage(cur ^ 1, ks + 1);   // prefetch next tile

        const bf16* Acur = &Asm[cur][0];
        const bf16* Bcur = &Bsm[cur][0];
        bf16x8 af[4], bfr[4];
#pragma unroll
        for (int mi = 0; mi < 4; ++mi)
            af[mi] = *(const bf16x8*)&Acur[(wr * 64 + mi * 16 + lrow) * kBK + rcs];
#pragma unroll
        for (int nj = 0; nj < 4; ++nj)
            bfr[nj] = *(const bf16x8*)&Bcur[(wc * 64 + nj * 16 + lrow) * kBK + rcs];
#pragma unroll
        for (int mi = 0; mi < 4; ++mi)
#pragma unroll
            for (int nj = 0; nj < 4; ++nj)
                acc[mi][nj] = __builtin_amdgcn_mfma_f32_16x16x32_bf16(
                    af[mi], bfr[nj], acc[mi][nj], 0, 0, 0);

        // single fused drain+barrier: prefetch latency lived under this body
        asm volatile("s_waitcnt vmcnt(0)\ns_barrier" ::: "memory");
        cur ^= 1;
    }

    // epilogue: C/D layout col=lane&15 (pixel), row=(lane>>4)*4+reg (oc)
#pragma unroll
    for (int nj = 0; nj < 4; ++nj) {
        const int gp = p0 + wc * 64 + nj * 16 + lrow;
        const int bb = gp / kPlane;
        const int qq = gp - bb * kPlane;
        float* ob = out + (size_t)bb * (kOC * kPlane) + qq;
#pragma unroll
        for (int mi = 0; mi < 4; ++mi) {
            const int o = ocb + wr * 64 + mi * 16 + (lane >> 4) * 4;
            float* op = ob + (size_t)o * kPlane;
#pragma unroll
            for (int r = 0; r < 4; ++r)
                op[(size_t)r * kPlane] = acc[mi][nj][r];
        }
    }
}

extern "C" void kernel_launch(void* const* d_in, const int* in_sizes, int n_in,
                              void* d_out, int out_size, void* d_ws, size_t ws_size,
                              hipStream_t stream) {
    const float* x = (const float*)d_in[0];
    const float* U = (const float*)d_in[1];
    const float* V = (const float*)d_in[2];
    float* out = (float*)d_out;

    // workspace layout
    bf16* Wb = (bf16*)d_ws;                                     // 9*256*256 bf16 = 1.18 MB
    bf16* xt = (bf16*)((char*)d_ws + (size_t)9 * kOC * kC * 2); // 32*58*58*256 bf16 = 55 MB

    merge_weights<<<dim3(9 * kOC), dim3(kC), 0, stream>>>(U, V, Wb);
    pad_nhwc<<<dim3(kB * kHP), dim3(256), 0, stream>>>(x, xt);
    conv_mfma<<<dim3(kNPix / kBN * (kOC / kBM)), dim3(256), 0, stream>>>(Wb, xt, out);
}